// Round 1
// baseline (111.781 us; speedup 1.0000x reference)
//
#include <hip/hip_runtime.h>

#define N_NODES 120000
#define K_NBR   16
#define F       64

// Kernel 1: T = feat @ theta_w ; B = T + feat @ phi_w + theta_b + phi_b
// 64 threads per row (o = output column), 4 rows per 256-thread block,
// weight columns held in registers, feat rows broadcast via LDS.
__global__ __launch_bounds__(256) void edgeconv_gemm(
    const float* __restrict__ feat,
    const float* __restrict__ theta_w,
    const float* __restrict__ theta_b,
    const float* __restrict__ phi_w,
    const float* __restrict__ phi_b,
    float* __restrict__ T,     // [N,64] scratch
    float* __restrict__ B)     // [N,64] -> d_out (consumed by kernel 2)
{
    __shared__ float srow[4 * F];
    const int tid = threadIdx.x;
    const int rb  = tid >> 6;      // row within block, 0..3
    const int o   = tid & 63;      // output column

    // Column o of both weight matrices into registers (static indexing via
    // full unroll so they stay in VGPRs, not scratch).
    float wt[F], wp[F];
    #pragma unroll
    for (int f = 0; f < F; ++f) {
        wt[f] = theta_w[f * F + o];
        wp[f] = phi_w[f * F + o];
    }
    const float bias_o = theta_b[o] + phi_b[o];

    for (int base = blockIdx.x * 4; base < N_NODES; base += gridDim.x * 4) {
        __syncthreads();                       // protect srow from prev iter
        srow[tid] = feat[base * F + tid];      // rows base..base+3, coalesced
        __syncthreads();

        float at = 0.f, ap = 0.f;
        const float4* sr4 = (const float4*)(&srow[rb * F]);
        #pragma unroll
        for (int ff = 0; ff < F / 4; ++ff) {
            float4 v = sr4[ff];                // same addr across wave: broadcast
            at += v.x * wt[4*ff+0]; ap += v.x * wp[4*ff+0];
            at += v.y * wt[4*ff+1]; ap += v.y * wp[4*ff+1];
            at += v.z * wt[4*ff+2]; ap += v.z * wp[4*ff+2];
            at += v.w * wt[4*ff+3]; ap += v.w * wp[4*ff+3];
        }
        const int r = base + rb;
        T[r * F + o] = at;
        B[r * F + o] = at + ap + bias_o;
    }
}

// Kernel 2: out[v][o] = B[v][o] - min_k T[nbr[v][k]][o]
// 64 lanes per node -> each neighbor row read is one coalesced 256B request.
__global__ __launch_bounds__(256) void edgeconv_minmax(
    const int* __restrict__ nbr,   // [N,16] int32
    const float* __restrict__ T,
    float* __restrict__ out)       // holds B on entry, result on exit
{
    const int tid = threadIdx.x;
    const int v   = blockIdx.x * 4 + (tid >> 6);
    const int o   = tid & 63;

    // 16 neighbor indices via four int4 loads (wave-uniform address -> broadcast)
    const int4* nb4 = (const int4*)nbr;
    int4 i0 = nb4[v * 4 + 0];
    int4 i1 = nb4[v * 4 + 1];
    int4 i2 = nb4[v * 4 + 2];
    int4 i3 = nb4[v * 4 + 3];
    int idx[16] = { i0.x, i0.y, i0.z, i0.w,
                    i1.x, i1.y, i1.z, i1.w,
                    i2.x, i2.y, i2.z, i2.w,
                    i3.x, i3.y, i3.z, i3.w };

    // Issue all 16 gathers independently, then reduce.
    float vals[16];
    #pragma unroll
    for (int k = 0; k < 16; ++k)
        vals[k] = T[idx[k] * F + o];

    float mn = vals[0];
    #pragma unroll
    for (int k = 1; k < 16; ++k)
        mn = fminf(mn, vals[k]);

    const float b = out[v * F + o];
    out[v * F + o] = b - mn;
}

extern "C" void kernel_launch(void* const* d_in, const int* in_sizes, int n_in,
                              void* d_out, int out_size, void* d_ws, size_t ws_size,
                              hipStream_t stream) {
    const float* feat    = (const float*)d_in[0];
    const int*   nbr     = (const int*)  d_in[1];
    const float* theta_w = (const float*)d_in[2];
    const float* theta_b = (const float*)d_in[3];
    const float* phi_w   = (const float*)d_in[4];
    const float* phi_b   = (const float*)d_in[5];
    float* out = (float*)d_out;
    float* T   = (float*)d_ws;   // 120000*64*4 = 30.7 MB scratch

    edgeconv_gemm<<<2048, 256, 0, stream>>>(feat, theta_w, theta_b, phi_w, phi_b, T, out);
    edgeconv_minmax<<<N_NODES / 4, 256, 0, stream>>>(nbr, T, out);
}

// Round 2
// 93.452 us; speedup vs baseline: 1.1961x; 1.1961x over previous
//
#include <hip/hip_runtime.h>
#include <hip/hip_bf16.h>

#define N_NODES 120000
#define K_NBR   16
#define F       64

// Kernel 1: T = feat @ theta_w (stored bf16) ; B = T + feat @ phi_w + biases (f32, -> d_out)
__global__ __launch_bounds__(256) void edgeconv_gemm(
    const float* __restrict__ feat,
    const float* __restrict__ theta_w,
    const float* __restrict__ theta_b,
    const float* __restrict__ phi_w,
    const float* __restrict__ phi_b,
    unsigned short* __restrict__ T16,  // [N,64] bf16 scratch
    float* __restrict__ B)             // [N,64] -> d_out (consumed by kernel 2)
{
    __shared__ float srow[4 * F];
    const int tid = threadIdx.x;
    const int rb  = tid >> 6;      // row within block, 0..3
    const int o   = tid & 63;      // output column

    float wt[F], wp[F];
    #pragma unroll
    for (int f = 0; f < F; ++f) {
        wt[f] = theta_w[f * F + o];
        wp[f] = phi_w[f * F + o];
    }
    const float bias_o = theta_b[o] + phi_b[o];

    for (int base = blockIdx.x * 4; base < N_NODES; base += gridDim.x * 4) {
        __syncthreads();
        srow[tid] = feat[base * F + tid];
        __syncthreads();

        float at = 0.f, ap = 0.f;
        const float4* sr4 = (const float4*)(&srow[rb * F]);
        #pragma unroll
        for (int ff = 0; ff < F / 4; ++ff) {
            float4 v = sr4[ff];
            at += v.x * wt[4*ff+0]; ap += v.x * wp[4*ff+0];
            at += v.y * wt[4*ff+1]; ap += v.y * wp[4*ff+1];
            at += v.z * wt[4*ff+2]; ap += v.z * wp[4*ff+2];
            at += v.w * wt[4*ff+3]; ap += v.w * wp[4*ff+3];
        }
        const int r = base + rb;
        // bf16 RNE via hip intrinsic
        T16[r * F + o] = __hip_bfloat16_raw(__float2bfloat16(at)).x;
        B[r * F + o] = at + ap + bias_o;
    }
}

// Kernel 2: out[v][o] = B[v][o] - min_k T[nbr[v][k]][o]   (T gathered as bf16)
__global__ __launch_bounds__(256) void edgeconv_minmax(
    const int* __restrict__ nbr,              // [N,16] int32
    const unsigned short* __restrict__ T16,   // [N,64] bf16
    float* __restrict__ out)                  // holds B on entry, result on exit
{
    const int tid = threadIdx.x;
    const int v   = blockIdx.x * 4 + (tid >> 6);
    const int o   = tid & 63;

    const int4* nb4 = (const int4*)nbr;
    int4 i0 = nb4[v * 4 + 0];
    int4 i1 = nb4[v * 4 + 1];
    int4 i2 = nb4[v * 4 + 2];
    int4 i3 = nb4[v * 4 + 3];
    int idx[16] = { i0.x, i0.y, i0.z, i0.w,
                    i1.x, i1.y, i1.z, i1.w,
                    i2.x, i2.y, i2.z, i2.w,
                    i3.x, i3.y, i3.z, i3.w };

    // 16 independent gathered bf16 loads (each: 64 lanes x 2B = 128B coalesced)
    unsigned short raw[16];
    #pragma unroll
    for (int k = 0; k < 16; ++k)
        raw[k] = T16[idx[k] * F + o];

    float mn = __uint_as_float((unsigned int)raw[0] << 16);
    #pragma unroll
    for (int k = 1; k < 16; ++k)
        mn = fminf(mn, __uint_as_float((unsigned int)raw[k] << 16));

    const float b = out[v * F + o];
    out[v * F + o] = b - mn;
}

extern "C" void kernel_launch(void* const* d_in, const int* in_sizes, int n_in,
                              void* d_out, int out_size, void* d_ws, size_t ws_size,
                              hipStream_t stream) {
    const float* feat    = (const float*)d_in[0];
    const int*   nbr     = (const int*)  d_in[1];
    const float* theta_w = (const float*)d_in[2];
    const float* theta_b = (const float*)d_in[3];
    const float* phi_w   = (const float*)d_in[4];
    const float* phi_b   = (const float*)d_in[5];
    float* out = (float*)d_out;
    unsigned short* T16 = (unsigned short*)d_ws;  // 120000*64*2 = 15.3 MB scratch

    edgeconv_gemm<<<2048, 256, 0, stream>>>(feat, theta_w, theta_b, phi_w, phi_b, T16, out);
    edgeconv_minmax<<<N_NODES / 4, 256, 0, stream>>>(nbr, T16, out);
}

// Round 3
// 62.509 us; speedup vs baseline: 1.7882x; 1.4950x over previous
//
#include <hip/hip_runtime.h>
#include <hip/hip_bf16.h>

#define N_NODES 120000
#define F       64

typedef __attribute__((ext_vector_type(8))) short bf16x8;   // 4 VGPRs
typedef __attribute__((ext_vector_type(4))) float f32x4;    // MFMA C/D

static __device__ __forceinline__ unsigned short f2bf(float x) {
    return __hip_bfloat16_raw(__float2bfloat16(x)).x;   // RNE
}

// Pack theta_w/phi_w into per-lane MFMA B-operand fragments (bf16).
// slot s = (mat*4 + c)*2 + kb ; lane l element e = W[kb*32 + (l>>4)*8 + e][c*16 + (l&15)]
__global__ void prep_weights(const float* __restrict__ theta_w,
                             const float* __restrict__ phi_w,
                             unsigned short* __restrict__ wfrag)  // [16][64][8]
{
    const int t    = threadIdx.x;          // 0..1023
    const int slot = t >> 6, lane = t & 63;
    const int mat  = slot >> 3, c = (slot >> 1) & 3, kb = slot & 1;
    const float* W = mat ? phi_w : theta_w;
    const int k0   = kb * 32 + ((lane >> 4) * 8);
    const int col  = c * 16 + (lane & 15);
    bf16x8 v;
    #pragma unroll
    for (int e = 0; e < 8; ++e)
        v[e] = (short)f2bf(W[(k0 + e) * F + col]);
    ((bf16x8*)wfrag)[slot * 64 + lane] = v;
}

// Kernel 1 (MFMA): T = feat@theta (bf16 out), B = T + feat@phi + biases (f32 -> d_out)
// One 16-row tile per wave; 16x16x32 bf16 MFMA; K=64 -> 2 k-steps; 4 col-tiles x 2 mats.
__global__ __launch_bounds__(256) void edgeconv_mfma(
    const float* __restrict__ feat,
    const unsigned short* __restrict__ wfrag,
    const float* __restrict__ theta_b,
    const float* __restrict__ phi_b,
    unsigned short* __restrict__ T16,
    float* __restrict__ B)
{
    const int lane = threadIdx.x & 63;
    const int wv   = threadIdx.x >> 6;
    const int tile = blockIdx.x * 4 + wv;      // 0..7499
    const int r0   = tile * 16;

    // Weight fragments: 16 coalesced 16B loads, L2-resident (16 KB total).
    const bf16x8* wf = (const bf16x8*)wfrag;
    bf16x8 wt[4][2], wp[4][2];
    #pragma unroll
    for (int c = 0; c < 4; ++c) {
        #pragma unroll
        for (int kb = 0; kb < 2; ++kb) {
            wt[c][kb] = wf[((0 * 4 + c) * 2 + kb) * 64 + lane];
            wp[c][kb] = wf[((1 * 4 + c) * 2 + kb) * 64 + lane];
        }
    }

    // A fragments: lane holds row (lane&15), k = (lane>>4)*8 + e (+32 for kb=1).
    const int arow = r0 + (lane & 15);
    const int k0   = (lane >> 4) * 8;
    const float4* f0 = (const float4*)(feat + arow * F + k0);
    const float4* f1 = (const float4*)(feat + arow * F + 32 + k0);
    float4 a0 = f0[0], a1 = f0[1];
    float4 a2 = f1[0], a3 = f1[1];
    bf16x8 afr0, afr1;
    afr0[0]=(short)f2bf(a0.x); afr0[1]=(short)f2bf(a0.y); afr0[2]=(short)f2bf(a0.z); afr0[3]=(short)f2bf(a0.w);
    afr0[4]=(short)f2bf(a1.x); afr0[5]=(short)f2bf(a1.y); afr0[6]=(short)f2bf(a1.z); afr0[7]=(short)f2bf(a1.w);
    afr1[0]=(short)f2bf(a2.x); afr1[1]=(short)f2bf(a2.y); afr1[2]=(short)f2bf(a2.z); afr1[3]=(short)f2bf(a2.w);
    afr1[4]=(short)f2bf(a3.x); afr1[5]=(short)f2bf(a3.y); afr1[6]=(short)f2bf(a3.z); afr1[7]=(short)f2bf(a3.w);

    f32x4 accT[4], accP[4];
    #pragma unroll
    for (int c = 0; c < 4; ++c) { accT[c] = (f32x4)(0.f); accP[c] = (f32x4)(0.f); }

    #pragma unroll
    for (int c = 0; c < 4; ++c) {
        accT[c] = __builtin_amdgcn_mfma_f32_16x16x32_bf16(afr0, wt[c][0], accT[c], 0, 0, 0);
        accT[c] = __builtin_amdgcn_mfma_f32_16x16x32_bf16(afr1, wt[c][1], accT[c], 0, 0, 0);
        accP[c] = __builtin_amdgcn_mfma_f32_16x16x32_bf16(afr0, wp[c][0], accP[c], 0, 0, 0);
        accP[c] = __builtin_amdgcn_mfma_f32_16x16x32_bf16(afr1, wp[c][1], accP[c], 0, 0, 0);
    }

    // Epilogue: D layout col = lane&15, row = (lane>>4)*4 + reg.
    const int colbase = lane & 15;
    const int rowbase = (lane >> 4) * 4;
    #pragma unroll
    for (int c = 0; c < 4; ++c) {
        const int col  = c * 16 + colbase;
        const float bo = theta_b[col] + phi_b[col];
        #pragma unroll
        for (int rg = 0; rg < 4; ++rg) {
            const int r = r0 + rowbase + rg;
            const float t = accT[c][rg];
            T16[r * F + col] = f2bf(t);
            B[r * F + col]   = t + accP[c][rg] + bo;
        }
    }
}

// Kernel 2: out[v][o] = B[v][o] - min_k T[nbr[v][k]][o]   (T gathered as bf16)
__global__ __launch_bounds__(256) void edgeconv_minmax(
    const int* __restrict__ nbr,
    const unsigned short* __restrict__ T16,
    float* __restrict__ out)
{
    const int tid = threadIdx.x;
    const int v   = blockIdx.x * 4 + (tid >> 6);
    const int o   = tid & 63;

    const int4* nb4 = (const int4*)nbr;
    int4 i0 = nb4[v * 4 + 0];
    int4 i1 = nb4[v * 4 + 1];
    int4 i2 = nb4[v * 4 + 2];
    int4 i3 = nb4[v * 4 + 3];
    int idx[16] = { i0.x, i0.y, i0.z, i0.w,
                    i1.x, i1.y, i1.z, i1.w,
                    i2.x, i2.y, i2.z, i2.w,
                    i3.x, i3.y, i3.z, i3.w };

    unsigned short raw[16];
    #pragma unroll
    for (int k = 0; k < 16; ++k)
        raw[k] = T16[idx[k] * F + o];

    float mn = __uint_as_float((unsigned int)raw[0] << 16);
    #pragma unroll
    for (int k = 1; k < 16; ++k)
        mn = fminf(mn, __uint_as_float((unsigned int)raw[k] << 16));

    const float b = out[v * F + o];
    out[v * F + o] = b - mn;
}

extern "C" void kernel_launch(void* const* d_in, const int* in_sizes, int n_in,
                              void* d_out, int out_size, void* d_ws, size_t ws_size,
                              hipStream_t stream) {
    const float* feat    = (const float*)d_in[0];
    const int*   nbr     = (const int*)  d_in[1];
    const float* theta_w = (const float*)d_in[2];
    const float* theta_b = (const float*)d_in[3];
    const float* phi_w   = (const float*)d_in[4];
    const float* phi_b   = (const float*)d_in[5];
    float* out = (float*)d_out;

    unsigned short* wfrag = (unsigned short*)d_ws;                 // 16 KB
    unsigned short* T16   = (unsigned short*)((char*)d_ws + 16384); // 15.36 MB

    prep_weights<<<1, 1024, 0, stream>>>(theta_w, phi_w, wfrag);
    edgeconv_mfma<<<N_NODES / 64, 256, 0, stream>>>(feat, wfrag, theta_b, phi_b, T16, out);
    edgeconv_minmax<<<N_NODES / 4, 256, 0, stream>>>(nbr, T16, out);
}

// Round 4
// 60.137 us; speedup vs baseline: 1.8588x; 1.0394x over previous
//
#include <hip/hip_runtime.h>
#include <hip/hip_bf16.h>

#define N_NODES 120000
#define F       64

typedef __attribute__((ext_vector_type(8))) short bf16x8;   // 4 VGPRs
typedef __attribute__((ext_vector_type(4))) float f32x4;    // MFMA C/D

static __device__ __forceinline__ unsigned short f2bf(float x) {
    return __hip_bfloat16_raw(__float2bfloat16(x)).x;   // RNE
}

// Pack theta_w/phi_w into per-lane MFMA B-operand fragments (bf16).
__global__ void prep_weights(const float* __restrict__ theta_w,
                             const float* __restrict__ phi_w,
                             unsigned short* __restrict__ wfrag)  // [16][64][8]
{
    const int t    = threadIdx.x;          // 0..1023
    const int slot = t >> 6, lane = t & 63;
    const int mat  = slot >> 3, c = (slot >> 1) & 3, kb = slot & 1;
    const float* W = mat ? phi_w : theta_w;
    const int k0   = kb * 32 + ((lane >> 4) * 8);
    const int col  = c * 16 + (lane & 15);
    bf16x8 v;
    #pragma unroll
    for (int e = 0; e < 8; ++e)
        v[e] = (short)f2bf(W[(k0 + e) * F + col]);
    ((bf16x8*)wfrag)[slot * 64 + lane] = v;
}

// Kernel 1 (MFMA): T16 = bf16(feat@theta); B16 = bf16(T + feat@phi + biases)
__global__ __launch_bounds__(256) void edgeconv_mfma(
    const float* __restrict__ feat,
    const unsigned short* __restrict__ wfrag,
    const float* __restrict__ theta_b,
    const float* __restrict__ phi_b,
    unsigned short* __restrict__ T16,
    unsigned short* __restrict__ B16)
{
    const int lane = threadIdx.x & 63;
    const int wv   = threadIdx.x >> 6;
    const int tile = blockIdx.x * 4 + wv;
    const int r0   = tile * 16;

    const bf16x8* wf = (const bf16x8*)wfrag;
    bf16x8 wt[4][2], wp[4][2];
    #pragma unroll
    for (int c = 0; c < 4; ++c) {
        #pragma unroll
        for (int kb = 0; kb < 2; ++kb) {
            wt[c][kb] = wf[((0 * 4 + c) * 2 + kb) * 64 + lane];
            wp[c][kb] = wf[((1 * 4 + c) * 2 + kb) * 64 + lane];
        }
    }

    const int arow = r0 + (lane & 15);
    const int k0   = (lane >> 4) * 8;
    const float4* f0 = (const float4*)(feat + arow * F + k0);
    const float4* f1 = (const float4*)(feat + arow * F + 32 + k0);
    float4 a0 = f0[0], a1 = f0[1];
    float4 a2 = f1[0], a3 = f1[1];
    bf16x8 afr0, afr1;
    afr0[0]=(short)f2bf(a0.x); afr0[1]=(short)f2bf(a0.y); afr0[2]=(short)f2bf(a0.z); afr0[3]=(short)f2bf(a0.w);
    afr0[4]=(short)f2bf(a1.x); afr0[5]=(short)f2bf(a1.y); afr0[6]=(short)f2bf(a1.z); afr0[7]=(short)f2bf(a1.w);
    afr1[0]=(short)f2bf(a2.x); afr1[1]=(short)f2bf(a2.y); afr1[2]=(short)f2bf(a2.z); afr1[3]=(short)f2bf(a2.w);
    afr1[4]=(short)f2bf(a3.x); afr1[5]=(short)f2bf(a3.y); afr1[6]=(short)f2bf(a3.z); afr1[7]=(short)f2bf(a3.w);

    f32x4 accT[4], accP[4];
    #pragma unroll
    for (int c = 0; c < 4; ++c) { accT[c] = (f32x4)(0.f); accP[c] = (f32x4)(0.f); }

    #pragma unroll
    for (int c = 0; c < 4; ++c) {
        accT[c] = __builtin_amdgcn_mfma_f32_16x16x32_bf16(afr0, wt[c][0], accT[c], 0, 0, 0);
        accT[c] = __builtin_amdgcn_mfma_f32_16x16x32_bf16(afr1, wt[c][1], accT[c], 0, 0, 0);
        accP[c] = __builtin_amdgcn_mfma_f32_16x16x32_bf16(afr0, wp[c][0], accP[c], 0, 0, 0);
        accP[c] = __builtin_amdgcn_mfma_f32_16x16x32_bf16(afr1, wp[c][1], accP[c], 0, 0, 0);
    }

    const int colbase = lane & 15;
    const int rowbase = (lane >> 4) * 4;
    #pragma unroll
    for (int c = 0; c < 4; ++c) {
        const int col  = c * 16 + colbase;
        const float bo = theta_b[col] + phi_b[col];
        #pragma unroll
        for (int rg = 0; rg < 4; ++rg) {
            const int r = r0 + rowbase + rg;
            const float t = accT[c][rg];
            T16[r * F + col] = f2bf(t);
            B16[r * F + col] = f2bf(t + accP[c][rg] + bo);
        }
    }
}

// Kernel 2: out[v][o] = B[v][o] - min_k T[nbr[v][k]][o]
// 2 nodes per wave, 2 bf16 columns per lane (uint gathers, 32-bit offsets).
__global__ __launch_bounds__(256) void edgeconv_minmax(
    const int* __restrict__ nbr,              // [N,16] int32
    const unsigned short* __restrict__ T16,   // [N,64] bf16
    const unsigned short* __restrict__ B16,   // [N,64] bf16
    float* __restrict__ out)                  // [N,64] f32
{
    const int tid  = threadIdx.x;
    const int lane = tid & 63;
    const int wv   = tid >> 6;
    const int half = lane >> 5;       // node within wave
    const int j    = lane & 31;       // column pair: cols 2j, 2j+1
    const int v    = blockIdx.x * 8 + wv * 2 + half;

    // 16 neighbor indices (uniform within each half-wave)
    const int4* nb4 = (const int4*)(nbr + v * 16);
    int4 i0 = nb4[0], i1 = nb4[1], i2 = nb4[2], i3 = nb4[3];
    int idx[16] = { i0.x, i0.y, i0.z, i0.w,
                    i1.x, i1.y, i1.z, i1.w,
                    i2.x, i2.y, i2.z, i2.w,
                    i3.x, i3.y, i3.z, i3.w };

    const unsigned int co = (unsigned int)(j << 2);   // byte offset within row

    // 16 independent 32-bit gathers (each half-wave: 32 lanes x 4B = 128B line)
    unsigned int u[16];
    #pragma unroll
    for (int k = 0; k < 16; ++k)
        u[k] = *(const unsigned int*)((const char*)T16 + ((((unsigned int)idx[k]) << 7) + co));

    float mlo = __uint_as_float(u[0] << 16);
    float mhi = __uint_as_float(u[0] & 0xffff0000u);
    #pragma unroll
    for (int k = 1; k < 16; ++k) {
        mlo = fminf(mlo, __uint_as_float(u[k] << 16));
        mhi = fminf(mhi, __uint_as_float(u[k] & 0xffff0000u));
    }

    const unsigned int bu = *(const unsigned int*)((const char*)B16 + ((((unsigned int)v) << 7) + co));
    const float blo = __uint_as_float(bu << 16);
    const float bhi = __uint_as_float(bu & 0xffff0000u);

    float2 res = make_float2(blo - mlo, bhi - mhi);
    *(float2*)(out + v * F + 2 * j) = res;
}

extern "C" void kernel_launch(void* const* d_in, const int* in_sizes, int n_in,
                              void* d_out, int out_size, void* d_ws, size_t ws_size,
                              hipStream_t stream) {
    const float* feat    = (const float*)d_in[0];
    const int*   nbr     = (const int*)  d_in[1];
    const float* theta_w = (const float*)d_in[2];
    const float* theta_b = (const float*)d_in[3];
    const float* phi_w   = (const float*)d_in[4];
    const float* phi_b   = (const float*)d_in[5];
    float* out = (float*)d_out;

    unsigned short* wfrag = (unsigned short*)d_ws;                        // 16 KB
    unsigned short* T16   = (unsigned short*)((char*)d_ws + 16384);      // 15.36 MB
    unsigned short* B16   = (unsigned short*)((char*)d_ws + 16384 + 15360000);

    prep_weights<<<1, 1024, 0, stream>>>(theta_w, phi_w, wfrag);
    edgeconv_mfma<<<N_NODES / 64, 256, 0, stream>>>(feat, wfrag, theta_b, phi_b, T16, B16);
    edgeconv_minmax<<<N_NODES / 8, 256, 0, stream>>>(nbr, T16, B16, out);
}